// Round 1
// baseline (16135.555 us; speedup 1.0000x reference)
//
#include <hip/hip_runtime.h>

#ifndef M_PI
#define M_PI 3.14159265358979323846
#endif

#define T_DATA 20000
#define E_NO_C 2000
#define I_NO_C 500
#define SUB 16
#define TNO 200

// ---------------- Kernel A: filter kernels (e, i, spk, hist) -> d_out[320000..] ----------------
// Rows: 0-15 e_kern, 16-31 i_kern, 32-47 spk_kern, 48-63 hist_kern (vstack order).
__global__ void filters_k(const float* __restrict__ Tau_e, const float* __restrict__ Tau_i,
                          const float* __restrict__ W_e,  const float* __restrict__ W_i,
                          const float* __restrict__ D_e,  const float* __restrict__ D_i,
                          const float* __restrict__ Tau_spk, const float* __restrict__ W_spk,
                          const float* __restrict__ W_hist,
                          float* __restrict__ filt_out) {
  int id = blockIdx.x * blockDim.x + threadIdx.x;
  if (id >= 64 * TNO) return;
  int r = id / TNO, x = id % TNO;
  int s = r & 15, kind = r >> 4;
  double xd = (double)x;
  double val;
  if (kind == 0) {
    double te = xd - exp((double)D_e[s]); te = te > 0.0 ? te : 0.0;
    double tt = te / exp((double)Tau_e[s]);
    val = tt * exp(-tt) * exp((double)W_e[s]);
  } else if (kind == 1) {
    double ti = xd - exp((double)D_i[s]); ti = ti > 0.0 ? ti : 0.0;
    double tt = ti / exp((double)Tau_i[s]);
    val = -tt * exp(-tt) * exp((double)W_i[s]);
  } else if (kind == 2) {
    double tt = xd / exp((double)Tau_spk[s]);
    val = tt * exp(-tt) * exp((double)W_spk[s]);
  } else {
    double raw = 4.0 * log(xd + 1.0);   // COS_SCALE * log(x + COS_SHIFT)
    double acc = 0.0;
    for (int i = 0; i < 16; ++i) {
      double phi = (M_PI / 2.0) * (double)i;
      double b = (raw < phi - M_PI || raw > phi + M_PI) ? 0.0
                                                        : (0.5 * cos(raw - phi) + 0.5);
      acc += (double)W_hist[s * 16 + i] * b;
    }
    val = acc;
  }
  filt_out[id] = (float)val;
}

// ---------------- Kernel B: syn = S @ C^T  (out[t][s] = sum_e S[t][e]*C[s][e]) ----------------
// block 256: lane s = tid&15 (subunit), tt = tid>>4 (row in 16-row tile). 1250 blocks.
__global__ void synmm_k(const float* __restrict__ S, const float* __restrict__ C,
                        float* __restrict__ out, int E) {
  int tid = threadIdx.x;
  int s = tid & 15, tt = tid >> 4;
  long t = (long)blockIdx.x * 16 + tt;
  const float* Srow = S + t * E;
  const float* Crow = C + (long)s * E;
  float acc = 0.f;
  for (int e = 0; e < E; e += 4) {
    float4 a = *(const float4*)(Srow + e);   // broadcast across the 16 s-lanes
    float4 c = *(const float4*)(Crow + e);
    acc += a.x * c.x + a.y * c.y;
    acc += a.z * c.z + a.w * c.w;
  }
  out[t * 16 + s] = acc;
}

// ---------------- Kernel C: causal depthwise conv + Theta ----------------
// synTh[t][s] = Theta[s] + sum_{j<min(200,t)} ek[s][j]*syn_e[t-1-j][s] + ik[s][j]*syn_i[t-1-j][s]
__global__ void conv_k(const float* __restrict__ syn_e, const float* __restrict__ syn_i,
                       const float* __restrict__ filt, const float* __restrict__ Theta,
                       float* __restrict__ synTh) {
  __shared__ float ek[16][201];  // +1 pad breaks bank aliasing
  __shared__ float ik[16][201];
  int tid = threadIdx.x;
  for (int idx = tid; idx < 16 * TNO; idx += 256) {
    ek[idx / TNO][idx % TNO] = filt[idx];
    ik[idx / TNO][idx % TNO] = filt[16 * TNO + idx];
  }
  __syncthreads();
  int s = tid & 15, tt = tid >> 4;
  int t = blockIdx.x * 16 + tt;
  float acc = Theta[s];
  if (t >= TNO) {
#pragma unroll 4
    for (int j = 0; j < TNO; ++j) {
      int u = t - 1 - j;
      acc += ek[s][j] * syn_e[u * 16 + s] + ik[s][j] * syn_i[u * 16 + s];
    }
  } else {
    for (int j = 0; j < t; ++j) {
      int u = t - 1 - j;
      acc += ek[s][j] * syn_e[u * 16 + s] + ik[s][j] * syn_i[u * 16 + s];
    }
  }
  synTh[t * 16 + s] = acc;
}

// ---------------- Kernel D: sequential spiking scan, single wave ----------------
// Lane l: s = l&15 (subunit), q = l>>4 (tap chunk of 50). History ring with mirrored
// tail: slot u also stored at u+256 when u<200, so every step's 200-tap window is a
// contiguous range of positions -> ds_read_b32 with immediate offsets (no addr VALU).
__global__ __launch_bounds__(64, 1) void scan_k(const float* __restrict__ synTh,
                                                const float* __restrict__ filt,
                                                const float* __restrict__ C_den,
                                                float* __restrict__ spk_out) {
  __shared__ float ring[456][17];  // stride 17: <=2-way bank aliasing (free)
  __shared__ __align__(16) float praw[16];
  int l = threadIdx.x;
  int s = l & 15, q = l >> 4;
  for (int i = l; i < 456 * 17; i += 64) (&ring[0][0])[i] = 0.f;

  // Reversed coefficient preload: hk[jj] pairs with ring position base+jj (delay d = q*50+49-jj).
  float hk[50], sk[50];
  const float* histk = filt + (48 + s) * TNO;
  const float* spkk  = filt + (32 + s) * TNO;
#pragma unroll
  for (int jj = 0; jj < 50; ++jj) {
    int d = q * 50 + 49 - jj;
    hk[jj] = histk[d];
    sk[jj] = spkk[d];
  }
  float cden[16];
#pragma unroll
  for (int i = 0; i < 16; ++i) cden[i] = C_den[s * 16 + i];
  __syncthreads();

  float synv = synTh[s];  // t = 0 value (prefetched each iter thereafter)
  for (int t = 0; t < T_DATA; ++t) {
    float synv_next = (t + 1 < T_DATA) ? synTh[(t + 1) * 16 + s] : 0.f;

    int W = (t - 1) & 255;        // window end position (delay d lives at W - d)
    if (W < 199) W += 256;        // use mirrored tail so window is contiguous
    const float* rp = &ring[W - q * 50 - 49][s];
    float h = 0.f, p = 0.f;
#pragma unroll
    for (int jj = 0; jj < 50; ++jj) {
      float sig = rp[jj * 17];
      h = fmaf(hk[jj], sig, h);
      p = fmaf(sk[jj], sig, p);
    }
    // reduce the 4 tap-chunks (lanes s, s+16, s+32, s+48)
    h += __shfl_xor(h, 16); h += __shfl_xor(h, 32);
    p += __shfl_xor(p, 16); p += __shfl_xor(p, 32);

    if (l < 16) praw[s] = p;
    __syncthreads();
    const float4* pv = (const float4*)praw;
    float4 p0 = pv[0], p1 = pv[1], p2 = pv[2], p3 = pv[3];
    float mix = cden[0] * p0.x + cden[1] * p0.y + cden[2]  * p0.z + cden[3]  * p0.w
              + cden[4] * p1.x + cden[5] * p1.y + cden[6]  * p1.z + cden[7]  * p1.w
              + cden[8] * p2.x + cden[9] * p2.y + cden[10] * p2.z + cden[11] * p2.w
              + cden[12]* p3.x + cden[13]* p3.y + cden[14] * p3.z + cden[15] * p3.w;

    float sub = h + mix + synv;
    float sig = sub > 0.f ? 1.f : 0.f;

    if (l < 16) {
      int u = t & 255;
      ring[u][s] = sig;
      if (u < 200) ring[u + 256][s] = sig;  // mirror tail
      spk_out[t * 16 + s] = sig;
    }
    synv = synv_next;
    __syncthreads();
  }
}

extern "C" void kernel_launch(void* const* d_in, const int* in_sizes, int n_in,
                              void* d_out, int out_size, void* d_ws, size_t ws_size,
                              hipStream_t stream) {
  const float* S_e     = (const float*)d_in[0];
  const float* S_i     = (const float*)d_in[1];
  const float* C_den   = (const float*)d_in[2];
  const float* C_syn_e = (const float*)d_in[3];
  const float* C_syn_i = (const float*)d_in[4];
  const float* Tau_e   = (const float*)d_in[5];
  const float* Tau_i   = (const float*)d_in[6];
  const float* W_e     = (const float*)d_in[7];
  const float* W_i     = (const float*)d_in[8];
  const float* D_e     = (const float*)d_in[9];
  const float* D_i     = (const float*)d_in[10];
  const float* Tau_spk = (const float*)d_in[11];
  const float* W_spk   = (const float*)d_in[12];
  const float* W_hist  = (const float*)d_in[13];
  const float* Theta   = (const float*)d_in[14];

  float* out     = (float*)d_out;
  float* spk_out = out;            // 20000*16 = 320000 floats
  float* filt    = out + 320000;   // 64*200 = 12800 floats (second tuple output)

  float* ws    = (float*)d_ws;     // needs 960000 floats = 3.84 MB
  float* syn_e = ws;               // 320000
  float* syn_i = ws + 320000;      // 320000
  float* synTh = ws + 640000;      // 320000

  filters_k<<<50, 256, 0, stream>>>(Tau_e, Tau_i, W_e, W_i, D_e, D_i,
                                    Tau_spk, W_spk, W_hist, filt);
  synmm_k<<<1250, 256, 0, stream>>>(S_e, C_syn_e, syn_e, E_NO_C);
  synmm_k<<<1250, 256, 0, stream>>>(S_i, C_syn_i, syn_i, I_NO_C);
  conv_k<<<1250, 256, 0, stream>>>(syn_e, syn_i, filt, Theta, synTh);
  scan_k<<<1, 64, 0, stream>>>(synTh, filt, C_den, spk_out);
}

// Round 3
// 6577.219 us; speedup vs baseline: 2.4532x; 2.4532x over previous
//
#include <hip/hip_runtime.h>

#ifndef M_PI
#define M_PI 3.14159265358979323846
#endif

#define T_DATA 20000
#define E_NO_C 2000
#define I_NO_C 500
#define SUB 16
#define TNO 200

// ---------------- Kernel A: filter kernels (e, i, spk, hist) -> d_out[320000..] ----------------
__global__ void filters_k(const float* __restrict__ Tau_e, const float* __restrict__ Tau_i,
                          const float* __restrict__ W_e,  const float* __restrict__ W_i,
                          const float* __restrict__ D_e,  const float* __restrict__ D_i,
                          const float* __restrict__ Tau_spk, const float* __restrict__ W_spk,
                          const float* __restrict__ W_hist,
                          float* __restrict__ filt_out) {
  int id = blockIdx.x * blockDim.x + threadIdx.x;
  if (id >= 64 * TNO) return;
  int r = id / TNO, x = id % TNO;
  int s = r & 15, kind = r >> 4;
  double xd = (double)x;
  double val;
  if (kind == 0) {
    double te = xd - exp((double)D_e[s]); te = te > 0.0 ? te : 0.0;
    double tt = te / exp((double)Tau_e[s]);
    val = tt * exp(-tt) * exp((double)W_e[s]);
  } else if (kind == 1) {
    double ti = xd - exp((double)D_i[s]); ti = ti > 0.0 ? ti : 0.0;
    double tt = ti / exp((double)Tau_i[s]);
    val = -tt * exp(-tt) * exp((double)W_i[s]);
  } else if (kind == 2) {
    double tt = xd / exp((double)Tau_spk[s]);
    val = tt * exp(-tt) * exp((double)W_spk[s]);
  } else {
    double raw = 4.0 * log(xd + 1.0);
    double acc = 0.0;
    for (int i = 0; i < 16; ++i) {
      double phi = (M_PI / 2.0) * (double)i;
      double b = (raw < phi - M_PI || raw > phi + M_PI) ? 0.0
                                                        : (0.5 * cos(raw - phi) + 0.5);
      acc += (double)W_hist[s * 16 + i] * b;
    }
    val = acc;
  }
  filt_out[id] = (float)val;
}

// ---------------- Kernel B: syn = S @ C^T ----------------
__global__ void synmm_k(const float* __restrict__ S, const float* __restrict__ C,
                        float* __restrict__ out, int E) {
  int tid = threadIdx.x;
  int s = tid & 15, tt = tid >> 4;
  long t = (long)blockIdx.x * 16 + tt;
  const float* Srow = S + t * E;
  const float* Crow = C + (long)s * E;
  float acc = 0.f;
  for (int e = 0; e < E; e += 4) {
    float4 a = *(const float4*)(Srow + e);
    float4 c = *(const float4*)(Crow + e);
    acc += a.x * c.x + a.y * c.y;
    acc += a.z * c.z + a.w * c.w;
  }
  out[t * 16 + s] = acc;
}

// ---------------- Kernel C: causal depthwise conv + Theta ----------------
__global__ void conv_k(const float* __restrict__ syn_e, const float* __restrict__ syn_i,
                       const float* __restrict__ filt, const float* __restrict__ Theta,
                       float* __restrict__ synTh) {
  __shared__ float ek[16][201];
  __shared__ float ik[16][201];
  int tid = threadIdx.x;
  for (int idx = tid; idx < 16 * TNO; idx += 256) {
    ek[idx / TNO][idx % TNO] = filt[idx];
    ik[idx / TNO][idx % TNO] = filt[16 * TNO + idx];
  }
  __syncthreads();
  int s = tid & 15, tt = tid >> 4;
  int t = blockIdx.x * 16 + tt;
  float acc = Theta[s];
  if (t >= TNO) {
#pragma unroll 4
    for (int j = 0; j < TNO; ++j) {
      int u = t - 1 - j;
      acc += ek[s][j] * syn_e[u * 16 + s] + ik[s][j] * syn_i[u * 16 + s];
    }
  } else {
    for (int j = 0; j < t; ++j) {
      int u = t - 1 - j;
      acc += ek[s][j] * syn_e[u * 16 + s] + ik[s][j] * syn_i[u * 16 + s];
    }
  }
  synTh[t * 16 + s] = acc;
}

// ---------------- Kernel D: wave-synchronous 4-step-grouped scan ----------------
// Shared gather covers delays 4..200 for ALL four in-group steps (g[0..2] zeroed on
// q=0 — h-indices 0..2 = delays 1..3 are ALWAYS supplied by corr's register history).
// spk: exact 2nd-order IIR in fp64; y broadcast via parity-double-buffered 16-float
// LDS written 2 steps ahead of use (spk_kern[0]=0 gives the 2-step injection slack).
__global__ __launch_bounds__(64, 1) void scan2_k(const float* __restrict__ synTh,
                                                 const float* __restrict__ filt,
                                                 const float* __restrict__ C_den,
                                                 const float* __restrict__ Tau_spk,
                                                 const float* __restrict__ W_spk,
                                                 float* __restrict__ spk_out) {
  __shared__ __align__(16) float ring[16][484];   // stride 484 ≡ 4 (mod 32): 2-way (free)
  __shared__ __align__(16) float praw_y[2][16];
  const int l = threadIdx.x;
  const int s = l & 15, q = l >> 4;

  for (int i = l; i < 16 * 484; i += 64) (&ring[0][0])[i] = 0.f;
  if (l < 32) (&praw_y[0][0])[l] = 0.f;

  const float* hrow = filt + (48 + s) * TNO;   // hist_kern row s
  float g[55];
#pragma unroll
  for (int jl = 0; jl < 55; ++jl) {
    int j = 52 * q + jl;
    g[jl] = (j < TNO) ? hrow[j] : 0.f;
  }
  if (q == 0) { g[0] = 0.f; g[1] = 0.f; g[2] = 0.f; }  // delays 1..3 live in corr, not the gather

  const float hk0 = hrow[0], hk1 = hrow[1], hk2 = hrow[2];

  float cden[16];
#pragma unroll
  for (int i = 0; i < 16; ++i) cden[i] = C_den[s * 16 + i];

  const double tau  = exp((double)Tau_spk[s]);
  const double aa   = exp(-1.0 / tau);
  const double ww   = exp((double)W_spk[s]);
  const double c2a  = ww * aa / tau;   // k[d] = C*(d-1)*a^(d-1), C = w/tau
  const double twoa = 2.0 * aa;
  const double na2  = -aa * aa;

  double yd0 = 0.0, yd1 = 0.0;          // y[t], y[t+1]
  float sig1 = 0.f, sig2 = 0.f, sig3 = 0.f;

  float syn0 = synTh[0 * 16 + s], syn1 = synTh[1 * 16 + s],
        syn2 = synTh[2 * 16 + s], syn3 = synTh[3 * 16 + s];

  const float* rowp = &ring[s][0];
  __builtin_amdgcn_wave_barrier();

#define GFMA(VAL, I)                                  \
  {                                                   \
    o0 = fmaf(g[51 - (I)], (VAL), o0);                \
    o1 = fmaf(g[52 - (I)], (VAL), o1);                \
    o2 = fmaf(g[53 - (I)], (VAL), o2);                \
    o3 = fmaf(g[54 - (I)], (VAL), o3);                \
  }

  for (int t0 = 0; t0 < T_DATA; t0 += 4) {
    // prefetch next group's synTh (one group of slack)
    float nsyn0 = 0.f, nsyn1 = 0.f, nsyn2 = 0.f, nsyn3 = 0.f;
    if (t0 + 4 < T_DATA) {
      nsyn0 = synTh[(t0 + 4) * 16 + s];
      nsyn1 = synTh[(t0 + 5) * 16 + s];
      nsyn2 = synTh[(t0 + 6) * 16 + s];
      nsyn3 = synTh[(t0 + 7) * 16 + s];
    }

    // shared hist gather: o_K = sum over old spikes, delays 4..200 (h-index m+K)
    int Pp = (t0 - 1) & 255;
    int P  = (Pp < 207) ? Pp + 256 : Pp;       // window end position (time t0-1)
    const float4* rp = (const float4*)(rowp + (P - 52 * q - 51));  // 16B-aligned
    float o0 = 0.f, o1 = 0.f, o2 = 0.f, o3 = 0.f;
#pragma unroll
    for (int j = 0; j < 13; ++j) {
      float4 vv = rp[j];                       // i = 4j+e, m = 52q+51-i, time t0-1-m
      GFMA(vv.x, 4 * j + 0);
      GFMA(vv.y, 4 * j + 1);
      GFMA(vv.z, 4 * j + 2);
      GFMA(vv.w, 4 * j + 3);
    }
    // reduce over the 4 m-chunks (lanes s, s+16, s+32, s+48)
    o0 += __shfl_xor(o0, 16); o0 += __shfl_xor(o0, 32);
    o1 += __shfl_xor(o1, 16); o1 += __shfl_xor(o1, 32);
    o2 += __shfl_xor(o2, 16); o2 += __shfl_xor(o2, 32);
    o3 += __shfl_xor(o3, 16); o3 += __shfl_xor(o3, 32);

#define STEP(K, OK, SYNK)                                                     \
    {                                                                         \
      const int t = t0 + (K);                                                 \
      const float4* yv = (const float4*)&praw_y[(K) & 1][0];                  \
      float4 ya = yv[0], yb = yv[1], yc = yv[2], yd = yv[3];                  \
      float mA = cden[0] * ya.x + cden[1] * ya.y + cden[2] * ya.z + cden[3] * ya.w;   \
      float mB = cden[4] * yb.x + cden[5] * yb.y + cden[6] * yb.z + cden[7] * yb.w;   \
      float mC = cden[8] * yc.x + cden[9] * yc.y + cden[10] * yc.z + cden[11] * yc.w; \
      float mD = cden[12] * yd.x + cden[13] * yd.y + cden[14] * yd.z + cden[15] * yd.w; \
      float mix = (mA + mB) + (mC + mD);                                      \
      float corr = fmaf(hk0, sig1, fmaf(hk1, sig2, hk2 * sig3));              \
      float sub = ((OK) + mix) + ((SYNK) + corr);                             \
      float sg = sub > 0.f ? 1.f : 0.f;                                       \
      if (l < 16) {                                                           \
        int u = t & 255;                                                      \
        ring[s][u] = sg;                                                      \
        if (u < 208) ring[s][u + 256] = sg;                                   \
        spk_out[t * 16 + s] = sg;                                             \
      }                                                                       \
      double y2 = fma(twoa, yd1, fma(na2, yd0, c2a * (double)sg));            \
      if (l < 16) praw_y[(K) & 1][s] = (float)y2;                             \
      yd0 = yd1; yd1 = y2;                                                    \
      sig3 = sig2; sig2 = sig1; sig1 = sg;                                    \
      __builtin_amdgcn_wave_barrier();                                        \
    }

    STEP(0, o0, syn0)
    STEP(1, o1, syn1)
    STEP(2, o2, syn2)
    STEP(3, o3, syn3)

    syn0 = nsyn0; syn1 = nsyn1; syn2 = nsyn2; syn3 = nsyn3;
  }
#undef STEP
#undef GFMA
}

extern "C" void kernel_launch(void* const* d_in, const int* in_sizes, int n_in,
                              void* d_out, int out_size, void* d_ws, size_t ws_size,
                              hipStream_t stream) {
  const float* S_e     = (const float*)d_in[0];
  const float* S_i     = (const float*)d_in[1];
  const float* C_den   = (const float*)d_in[2];
  const float* C_syn_e = (const float*)d_in[3];
  const float* C_syn_i = (const float*)d_in[4];
  const float* Tau_e   = (const float*)d_in[5];
  const float* Tau_i   = (const float*)d_in[6];
  const float* W_e     = (const float*)d_in[7];
  const float* W_i     = (const float*)d_in[8];
  const float* D_e     = (const float*)d_in[9];
  const float* D_i     = (const float*)d_in[10];
  const float* Tau_spk = (const float*)d_in[11];
  const float* W_spk   = (const float*)d_in[12];
  const float* W_hist  = (const float*)d_in[13];
  const float* Theta   = (const float*)d_in[14];

  float* out     = (float*)d_out;
  float* spk_out = out;            // 20000*16
  float* filt    = out + 320000;   // 64*200

  float* ws    = (float*)d_ws;
  float* syn_e = ws;               // 320000
  float* syn_i = ws + 320000;      // 320000
  float* synTh = ws + 640000;      // 320000

  filters_k<<<50, 256, 0, stream>>>(Tau_e, Tau_i, W_e, W_i, D_e, D_i,
                                    Tau_spk, W_spk, W_hist, filt);
  synmm_k<<<1250, 256, 0, stream>>>(S_e, C_syn_e, syn_e, E_NO_C);
  synmm_k<<<1250, 256, 0, stream>>>(S_i, C_syn_i, syn_i, I_NO_C);
  conv_k<<<1250, 256, 0, stream>>>(syn_e, syn_i, filt, Theta, synTh);
  scan2_k<<<1, 64, 0, stream>>>(synTh, filt, C_den, Tau_spk, W_spk, spk_out);
}

// Round 4
// 4713.883 us; speedup vs baseline: 3.4230x; 1.3953x over previous
//
#include <hip/hip_runtime.h>

#ifndef M_PI
#define M_PI 3.14159265358979323846
#endif

#define T_DATA 20000
#define E_NO_C 2000
#define I_NO_C 500
#define SUB 16
#define TNO 200

typedef float v2f __attribute__((ext_vector_type(2)));

// ---------------- Kernel A: filter kernels (e, i, spk, hist) -> d_out[320000..] ----------------
__global__ void filters_k(const float* __restrict__ Tau_e, const float* __restrict__ Tau_i,
                          const float* __restrict__ W_e,  const float* __restrict__ W_i,
                          const float* __restrict__ D_e,  const float* __restrict__ D_i,
                          const float* __restrict__ Tau_spk, const float* __restrict__ W_spk,
                          const float* __restrict__ W_hist,
                          float* __restrict__ filt_out) {
  int id = blockIdx.x * blockDim.x + threadIdx.x;
  if (id >= 64 * TNO) return;
  int r = id / TNO, x = id % TNO;
  int s = r & 15, kind = r >> 4;
  double xd = (double)x;
  double val;
  if (kind == 0) {
    double te = xd - exp((double)D_e[s]); te = te > 0.0 ? te : 0.0;
    double tt = te / exp((double)Tau_e[s]);
    val = tt * exp(-tt) * exp((double)W_e[s]);
  } else if (kind == 1) {
    double ti = xd - exp((double)D_i[s]); ti = ti > 0.0 ? ti : 0.0;
    double tt = ti / exp((double)Tau_i[s]);
    val = -tt * exp(-tt) * exp((double)W_i[s]);
  } else if (kind == 2) {
    double tt = xd / exp((double)Tau_spk[s]);
    val = tt * exp(-tt) * exp((double)W_spk[s]);
  } else {
    double raw = 4.0 * log(xd + 1.0);
    double acc = 0.0;
    for (int i = 0; i < 16; ++i) {
      double phi = (M_PI / 2.0) * (double)i;
      double b = (raw < phi - M_PI || raw > phi + M_PI) ? 0.0
                                                        : (0.5 * cos(raw - phi) + 0.5);
      acc += (double)W_hist[s * 16 + i] * b;
    }
    val = acc;
  }
  filt_out[id] = (float)val;
}

// ---------------- Kernel B: syn = S @ C^T, C staged in LDS tiles ----------------
// All products/sums are exact small integers in fp32 (S,C in {0,1}) -> order-safe.
#define ETILE 500
__global__ __launch_bounds__(256) void synmm_k(const float* __restrict__ S,
                                               const float* __restrict__ C,
                                               float* __restrict__ out, int E) {
  __shared__ __align__(16) float Cs[16][ETILE];
  int tid = threadIdx.x;
  int s = tid & 15, tt = tid >> 4;
  long t = (long)blockIdx.x * 16 + tt;
  const float* Srow = S + t * E;
  float acc = 0.f;
  for (int tb = 0; tb < E; tb += ETILE) {
    __syncthreads();
    for (int i = tid; i < 16 * ETILE; i += 256) {
      int s2 = i / ETILE, k2 = i - s2 * ETILE;
      Cs[s2][k2] = C[(long)s2 * E + tb + k2];
    }
    __syncthreads();
    const float* Crow = &Cs[s][0];
    const float* Sp = Srow + tb;
#pragma unroll 2
    for (int e = 0; e < ETILE; e += 4) {
      float4 a = *(const float4*)(Sp + e);
      float4 c = *(const float4*)(Crow + e);
      acc = fmaf(a.x, c.x, acc); acc = fmaf(a.y, c.y, acc);
      acc = fmaf(a.z, c.z, acc); acc = fmaf(a.w, c.w, acc);
    }
  }
  out[t * 16 + s] = acc;
}

// ---------------- Kernel C: causal depthwise conv + Theta, TRANSPOSED output ----------------
// synT[s][t] = Theta[s] + sum_j ek[s][j]*syn_e[t-1-j][s] + ik[s][j]*syn_i[t-1-j][s]
__global__ void conv_k(const float* __restrict__ syn_e, const float* __restrict__ syn_i,
                       const float* __restrict__ filt, const float* __restrict__ Theta,
                       float* __restrict__ synT) {
  __shared__ float ek[16][201];
  __shared__ float ik[16][201];
  int tid = threadIdx.x;
  for (int idx = tid; idx < 16 * TNO; idx += 256) {
    ek[idx / TNO][idx % TNO] = filt[idx];
    ik[idx / TNO][idx % TNO] = filt[16 * TNO + idx];
  }
  __syncthreads();
  int s = tid & 15, tt = tid >> 4;
  int t = blockIdx.x * 16 + tt;
  float acc = Theta[s];
  if (t >= TNO) {
#pragma unroll 4
    for (int j = 0; j < TNO; ++j) {
      int u = t - 1 - j;
      acc += ek[s][j] * syn_e[u * 16 + s] + ik[s][j] * syn_i[u * 16 + s];
    }
  } else {
    for (int j = 0; j < t; ++j) {
      int u = t - 1 - j;
      acc += ek[s][j] * syn_e[u * 16 + s] + ik[s][j] * syn_i[u * 16 + s];
    }
  }
  synT[(long)s * T_DATA + t] = acc;
}

// ---------------- Kernel D: wave-sync scan, ballot broadcast + pipelined gather ----------------
// Per 4-step group: gather (delays >= K+5) reads issued one full group ahead of use;
// delays 1..K+4 from own-lane register history (corr). Spike broadcast via __ballot
// (scalar, zero LDS latency). spk IIR: exact 2nd-order fp64 recurrence per subunit,
// 4 subunits per lane, mix reduced over q via 2 xor-shuffles, produced 2 steps early.
__global__ __launch_bounds__(64, 1) void scan3_k(const float* __restrict__ synT,
                                                 const float* __restrict__ filt,
                                                 const float* __restrict__ C_den,
                                                 const float* __restrict__ Tau_spk,
                                                 const float* __restrict__ W_spk,
                                                 float* __restrict__ spk_out) {
  __shared__ __align__(16) float ring[16][484];   // [s][pos], mirrored tail pos+256 for pos<208
  const int l = threadIdx.x;
  const int s = l & 15, q = l >> 4;

  for (int i = l; i < 16 * 484; i += 64) (&ring[0][0])[i] = 0.f;

  const float* hrow = filt + (48 + s) * TNO;   // hist_kern row s
  float hk[7];
#pragma unroll
  for (int i = 0; i < 7; ++i) hk[i] = hrow[i];

  // gather coefficients: g[jl] = hrow[52q+4+jl] (h-index = delay-1; gather = delays >= 5+K)
  float g[55];
#pragma unroll
  for (int jl = 0; jl < 55; ++jl) {
    int hidx = 52 * q + 4 + jl;
    g[jl] = (hidx < TNO) ? hrow[hidx] : 0.f;
  }
  v2f GE[27], GO[27];
#pragma unroll
  for (int k = 0; k < 27; ++k) {
    GE[k].x = g[2 * k + 1]; GE[k].y = g[2 * k];
    GO[k].x = (2 * k + 2 < 55) ? g[2 * k + 2] : 0.f;
    GO[k].y = g[2 * k + 1];
  }

  float cden4[4];
#pragma unroll
  for (int r = 0; r < 4; ++r) cden4[r] = C_den[s * 16 + 4 * q + r];

  double twoa[4], na2[4], c2a[4], yd0[4], yd1[4];
#pragma unroll
  for (int r = 0; r < 4; ++r) {
    int j = 4 * q + r;
    double tauj = exp((double)Tau_spk[j]);
    double aj = exp(-1.0 / tauj);
    twoa[r] = 2.0 * aj;
    na2[r]  = -aj * aj;
    c2a[r]  = exp((double)W_spk[j]) * aj / tauj;   // k[d] = C*(d-1)*a^(d-1), C = w/tau
    yd0[r] = 0.0; yd1[r] = 0.0;
  }

  float sig1 = 0.f, sig2 = 0.f, sig3 = 0.f, sig4 = 0.f, sig5 = 0.f, sig6 = 0.f, sig7 = 0.f;
  float o0 = 0.f, o1 = 0.f, o2 = 0.f, o3 = 0.f;
  float mixA = 0.f, mixB = 0.f;
  float4 sv = *(const float4*)(synT + (long)s * T_DATA);

  const float* rowp = &ring[s][0];

#define DOSTEP(OV, SVV, MIXIN, MIXOUT, MASKV, CORR)                      \
  {                                                                      \
    float corr = (CORR);                                                 \
    float sub = ((OV) + (MIXIN)) + ((SVV) + corr);                       \
    unsigned long long bal = __ballot(sub > 0.f);                        \
    float sg = sub > 0.f ? 1.f : 0.f;                                    \
    (MASKV) = (unsigned)bal;                                             \
    sig7 = sig6; sig6 = sig5; sig5 = sig4; sig4 = sig3;                  \
    sig3 = sig2; sig2 = sig1; sig1 = sg;                                 \
    float p = 0.f;                                                       \
    _Pragma("unroll")                                                    \
    for (int r = 0; r < 4; ++r) {                                        \
      float x = (float)(((MASKV) >> (4 * q + r)) & 1u);                  \
      double y2 = fma(twoa[r], yd1[r],                                   \
                      fma(na2[r], yd0[r], c2a[r] * (double)x));          \
      yd0[r] = yd1[r]; yd1[r] = y2;                                      \
      p = fmaf(cden4[r], (float)y2, p);                                  \
    }                                                                    \
    p += __shfl_xor(p, 16); p += __shfl_xor(p, 32);                      \
    (MIXOUT) = p;                                                        \
  }

  for (int t0 = 0; t0 < T_DATA; t0 += 4) {
    // ---- top: issue reads for NEXT group's gather (window times <= t0-1, all written) ----
    int Pp = (t0 - 1) & 255;
    int P  = (Pp < 207) ? Pp + 256 : Pp;
    const float4* rp = (const float4*)(rowp + (P - 52 * q - 51));  // 16B-aligned
    float4 V[13];
#pragma unroll
    for (int j4 = 0; j4 < 13; ++j4) V[j4] = rp[j4];

    // prefetch next group's synT (one group of slack)
    float4 svn;
    if (t0 + 4 < T_DATA) svn = *(const float4*)(synT + (long)s * T_DATA + t0 + 4);
    else { svn.x = 0.f; svn.y = 0.f; svn.z = 0.f; svn.w = 0.f; }

    // ---- 4 steps ----
    unsigned mask0, mask1, mask2, mask3;
    float t2m, t3m;
    DOSTEP(o0, sv.x, mixA, t2m, mask0,
           fmaf(hk[3], sig4, fmaf(hk[2], sig3, fmaf(hk[1], sig2, hk[0] * sig1))))
    DOSTEP(o1, sv.y, mixB, t3m, mask1,
           fmaf(hk[4], sig5, fmaf(hk[3], sig4,
             fmaf(hk[2], sig3, fmaf(hk[1], sig2, hk[0] * sig1)))))
    DOSTEP(o2, sv.z, t2m, mixA, mask2,
           fmaf(hk[5], sig6, fmaf(hk[4], sig5, fmaf(hk[3], sig4,
             fmaf(hk[2], sig3, fmaf(hk[1], sig2, hk[0] * sig1))))))
    DOSTEP(o3, sv.w, t3m, mixB, mask3,
           fmaf(hk[6], sig7, fmaf(hk[5], sig6, fmaf(hk[4], sig5, fmaf(hk[3], sig4,
             fmaf(hk[2], sig3, fmaf(hk[1], sig2, hk[0] * sig1)))))))

    // ---- gather for next group (consumes V loaded at top: latency fully hidden) ----
    v2f acc0 = {0.f, 0.f}, acc1 = {0.f, 0.f}, acc2 = {0.f, 0.f}, acc3 = {0.f, 0.f};
#pragma unroll
    for (int j4 = 0; j4 < 13; ++j4) {
      v2f A; A.x = V[j4].x; A.y = V[j4].y;       // i = 4*j4
      const int k = 25 - 2 * j4;
      acc0 += GE[k] * A; acc1 += GO[k] * A;
      acc2 += GE[k + 1] * A; acc3 += GO[k + 1] * A;
      v2f B; B.x = V[j4].z; B.y = V[j4].w;       // i = 4*j4 + 2
      const int k2 = 24 - 2 * j4;
      acc0 += GE[k2] * B; acc1 += GO[k2] * B;
      acc2 += GE[k2 + 1] * B; acc3 += GO[k2 + 1] * B;
    }
    float n0 = acc0.x + acc0.y, n1 = acc1.x + acc1.y;
    float n2 = acc2.x + acc2.y, n3 = acc3.x + acc3.y;
    n0 += __shfl_xor(n0, 16); n0 += __shfl_xor(n0, 32);
    n1 += __shfl_xor(n1, 16); n1 += __shfl_xor(n1, 32);
    n2 += __shfl_xor(n2, 16); n2 += __shfl_xor(n2, 32);
    n3 += __shfl_xor(n3, 16); n3 += __shfl_xor(n3, 32);
    o0 = n0; o1 = n1; o2 = n2; o3 = n3;

    // ---- ring write: one b128 (+mirror) per group; sig4..sig1 = spikes t0..t0+3 ----
    if (l < 16) {
      int u = t0 & 255;
      float4 w; w.x = sig4; w.y = sig3; w.z = sig2; w.w = sig1;
      *(float4*)&ring[s][u] = w;
      if (u < 208) *(float4*)&ring[s][u + 256] = w;
    }

    // ---- spk_out: one coalesced 64-lane store; lane l -> (step q, subunit s) ----
    unsigned mm = (q == 0) ? mask0 : (q == 1) ? mask1 : (q == 2) ? mask2 : mask3;
    spk_out[t0 * 16 + l] = (float)((mm >> s) & 1u);

    mixA = mixA; mixB = mixB;   // (already rotated via DOSTEP outputs)
    sv = svn;
  }
#undef DOSTEP
}

extern "C" void kernel_launch(void* const* d_in, const int* in_sizes, int n_in,
                              void* d_out, int out_size, void* d_ws, size_t ws_size,
                              hipStream_t stream) {
  const float* S_e     = (const float*)d_in[0];
  const float* S_i     = (const float*)d_in[1];
  const float* C_den   = (const float*)d_in[2];
  const float* C_syn_e = (const float*)d_in[3];
  const float* C_syn_i = (const float*)d_in[4];
  const float* Tau_e   = (const float*)d_in[5];
  const float* Tau_i   = (const float*)d_in[6];
  const float* W_e     = (const float*)d_in[7];
  const float* W_i     = (const float*)d_in[8];
  const float* D_e     = (const float*)d_in[9];
  const float* D_i     = (const float*)d_in[10];
  const float* Tau_spk = (const float*)d_in[11];
  const float* W_spk   = (const float*)d_in[12];
  const float* W_hist  = (const float*)d_in[13];
  const float* Theta   = (const float*)d_in[14];

  float* out     = (float*)d_out;
  float* spk_out = out;            // 20000*16
  float* filt    = out + 320000;   // 64*200

  float* ws    = (float*)d_ws;
  float* syn_e = ws;               // 320000
  float* syn_i = ws + 320000;      // 320000
  float* synT  = ws + 640000;      // 320000 (transposed [s][t])

  filters_k<<<50, 256, 0, stream>>>(Tau_e, Tau_i, W_e, W_i, D_e, D_i,
                                    Tau_spk, W_spk, W_hist, filt);
  synmm_k<<<1250, 256, 0, stream>>>(S_e, C_syn_e, syn_e, E_NO_C);
  synmm_k<<<1250, 256, 0, stream>>>(S_i, C_syn_i, syn_i, I_NO_C);
  conv_k<<<1250, 256, 0, stream>>>(syn_e, syn_i, filt, Theta, synT);
  scan3_k<<<1, 64, 0, stream>>>(synT, filt, C_den, Tau_spk, W_spk, spk_out);
}

// Round 5
// 2919.543 us; speedup vs baseline: 5.5267x; 1.6146x over previous
//
#include <hip/hip_runtime.h>

#ifndef M_PI
#define M_PI 3.14159265358979323846
#endif

#define T_DATA 20000
#define E_NO_C 2000
#define I_NO_C 500
#define SUB 16
#define TNO 200
#define NGRP 5000

typedef float v2f __attribute__((ext_vector_type(2)));

// ---------------- Kernel A: filter kernels (e, i, spk, hist) -> d_out[320000..] ----------------
__global__ void filters_k(const float* __restrict__ Tau_e, const float* __restrict__ Tau_i,
                          const float* __restrict__ W_e,  const float* __restrict__ W_i,
                          const float* __restrict__ D_e,  const float* __restrict__ D_i,
                          const float* __restrict__ Tau_spk, const float* __restrict__ W_spk,
                          const float* __restrict__ W_hist,
                          float* __restrict__ filt_out) {
  int id = blockIdx.x * blockDim.x + threadIdx.x;
  if (id >= 64 * TNO) return;
  int r = id / TNO, x = id % TNO;
  int s = r & 15, kind = r >> 4;
  double xd = (double)x;
  double val;
  if (kind == 0) {
    double te = xd - exp((double)D_e[s]); te = te > 0.0 ? te : 0.0;
    double tt = te / exp((double)Tau_e[s]);
    val = tt * exp(-tt) * exp((double)W_e[s]);
  } else if (kind == 1) {
    double ti = xd - exp((double)D_i[s]); ti = ti > 0.0 ? ti : 0.0;
    double tt = ti / exp((double)Tau_i[s]);
    val = -tt * exp(-tt) * exp((double)W_i[s]);
  } else if (kind == 2) {
    double tt = xd / exp((double)Tau_spk[s]);
    val = tt * exp(-tt) * exp((double)W_spk[s]);
  } else {
    double raw = 4.0 * log(xd + 1.0);
    double acc = 0.0;
    for (int i = 0; i < 16; ++i) {
      double phi = (M_PI / 2.0) * (double)i;
      double b = (raw < phi - M_PI || raw > phi + M_PI) ? 0.0
                                                        : (0.5 * cos(raw - phi) + 0.5);
      acc += (double)W_hist[s * 16 + i] * b;
    }
    val = acc;
  }
  filt_out[id] = (float)val;
}

// ---------------- Kernel B: syn = S @ C^T, C staged in LDS tiles ----------------
#define ETILE 500
__global__ __launch_bounds__(256) void synmm_k(const float* __restrict__ S,
                                               const float* __restrict__ C,
                                               float* __restrict__ out, int E) {
  __shared__ __align__(16) float Cs[16][ETILE];
  int tid = threadIdx.x;
  int s = tid & 15, tt = tid >> 4;
  long t = (long)blockIdx.x * 16 + tt;
  const float* Srow = S + t * E;
  float acc = 0.f;
  for (int tb = 0; tb < E; tb += ETILE) {
    __syncthreads();
    for (int i = tid; i < 16 * ETILE; i += 256) {
      int s2 = i / ETILE, k2 = i - s2 * ETILE;
      Cs[s2][k2] = C[(long)s2 * E + tb + k2];
    }
    __syncthreads();
    const float* Crow = &Cs[s][0];
    const float* Sp = Srow + tb;
#pragma unroll 2
    for (int e = 0; e < ETILE; e += 4) {
      float4 a = *(const float4*)(Sp + e);
      float4 c = *(const float4*)(Crow + e);
      acc = fmaf(a.x, c.x, acc); acc = fmaf(a.y, c.y, acc);
      acc = fmaf(a.z, c.z, acc); acc = fmaf(a.w, c.w, acc);
    }
  }
  out[t * 16 + s] = acc;
}

// ---------------- Kernel C: causal depthwise conv + Theta, TRANSPOSED output ----------------
__global__ void conv_k(const float* __restrict__ syn_e, const float* __restrict__ syn_i,
                       const float* __restrict__ filt, const float* __restrict__ Theta,
                       float* __restrict__ synT) {
  __shared__ float ek[16][201];
  __shared__ float ik[16][201];
  int tid = threadIdx.x;
  for (int idx = tid; idx < 16 * TNO; idx += 256) {
    ek[idx / TNO][idx % TNO] = filt[idx];
    ik[idx / TNO][idx % TNO] = filt[16 * TNO + idx];
  }
  __syncthreads();
  int s = tid & 15, tt = tid >> 4;
  int t = blockIdx.x * 16 + tt;
  float acc = Theta[s];
  if (t >= TNO) {
#pragma unroll 4
    for (int j = 0; j < TNO; ++j) {
      int u = t - 1 - j;
      acc += ek[s][j] * syn_e[u * 16 + s] + ik[s][j] * syn_i[u * 16 + s];
    }
  } else {
    for (int j = 0; j < t; ++j) {
      int u = t - 1 - j;
      acc += ek[s][j] * syn_e[u * 16 + s] + ik[s][j] * syn_i[u * 16 + s];
    }
  }
  synT[(long)s * T_DATA + t] = acc;
}

// ---------------- Kernel D: 4-wave producer/consumer scan ----------------
// Wave 0 (scan): per step, corr(delays 1..K+8, regs) + mix(spk) via popcount-driven
//   fp64 IIR (uniform-tau fast path; general 4-IIR fallback) + ballot. Consumes hist
//   gather o[group] prefetched one iter early from LDS partials.
// Waves 1-3 (gather): split group G+2's hist gather (delays >= K+9; window = 192
//   positions ending at time 4G-1, all visible after the previous barrier).
// One __syncthreads per iteration; ring/oPart access patterns are disjoint (audited).
__global__ __launch_bounds__(256, 1) void scan4_k(const float* __restrict__ synT,
                                                  const float* __restrict__ filt,
                                                  const float* __restrict__ C_den,
                                                  const float* __restrict__ Tau_spk,
                                                  const float* __restrict__ W_spk,
                                                  float* __restrict__ spk_out) {
  __shared__ __align__(16) float ring[16][452];      // [s][pos], mirror pos+256 for pos<192
  __shared__ __align__(16) float oPart[3][3][16][4]; // [slot][wave][s][K]
  const int tid = threadIdx.x;
  const int widx = tid >> 6;
  const int l = tid & 63;
  const int s = l & 15, q = l >> 4;

  for (int i = tid; i < 16 * 452; i += 256) (&ring[0][0])[i] = 0.f;
  for (int i = tid; i < 3 * 3 * 16 * 4; i += 256) (&oPart[0][0][0][0])[i] = 0.f;
  __syncthreads();

  if (widx == 0) {
    // ================= scan wave =================
    const float* hrow = filt + (48 + s) * TNO;
    float hk[11];
#pragma unroll
    for (int i = 0; i < 11; ++i) hk[i] = hrow[i];

    // fast-path check: uniform tau/W, binary C_den
    float t0v = Tau_spk[0], w0v = W_spk[0];
    bool okrow = (Tau_spk[s] == t0v) && (W_spk[s] == w0v);
    unsigned cd = 0u;
#pragma unroll
    for (int j = 0; j < 16; ++j) {
      float cv = C_den[s * 16 + j];
      okrow = okrow && (cv == 0.f || cv == 1.f);
      cd |= (cv != 0.f) ? (1u << j) : 0u;
    }
    const bool uni = (bool)__all((int)okrow);

    const double tau  = exp((double)Tau_spk[s]);
    const double aa   = exp(-1.0 / tau);
    const double c2a  = exp((double)W_spk[s]) * aa / tau;  // K[d]=C(d-1)a^(d-1), C=w/tau
    const double twoa = 2.0 * aa;
    const double na2  = -aa * aa;

    // fallback (general) per-lane 4-subunit IIR constants
    double twoa4[4], na24[4], c2a4[4], yd0a[4], yd1a[4];
    float cden4[4];
#pragma unroll
    for (int r = 0; r < 4; ++r) {
      int j = 4 * q + r;
      double tj = exp((double)Tau_spk[j]);
      double aj = exp(-1.0 / tj);
      twoa4[r] = 2.0 * aj; na24[r] = -aj * aj;
      c2a4[r]  = exp((double)W_spk[j]) * aj / tj;
      yd0a[r] = 0.0; yd1a[r] = 0.0;
      cden4[r] = C_den[s * 16 + j];
    }

    double zA = 0.0, zB = 0.0;          // z_t, z_{t+1} (fast path)
    float mixu = 0.f, mix1 = 0.f;       // mix_t, mix_{t+1} (generic pipeline regs)
    float sig[11];
#pragma unroll
    for (int i = 0; i < 11; ++i) sig[i] = 0.f;

    float4 oc; oc.x = 0.f; oc.y = 0.f; oc.z = 0.f; oc.w = 0.f;   // group 0: zero
    float4 sv = *(const float4*)(synT + (long)s * T_DATA);

#define STEP(K, OV, SVV, MASKV)                                               \
    {                                                                         \
      float rest = 0.f;                                                       \
      _Pragma("unroll")                                                       \
      for (int d = 2; d <= (K) + 8; ++d) rest = fmaf(hk[d - 1], sig[d - 1], rest); \
      float pre = ((OV) + (SVV)) + (mixu + rest);                             \
      float sub = fmaf(hk[0], sig[0], pre);                                   \
      unsigned long long bal = __ballot(sub > 0.f);                           \
      float sg = sub > 0.f ? 1.f : 0.f;                                       \
      unsigned mk = (unsigned)bal & 0xFFFFu;                                  \
      (MASKV) = mk;                                                           \
      float mixn;                                                             \
      if (uni) {                                                              \
        double zc = fma(twoa, zB, fma(na2, zA, c2a * (double)__popc(mk & cd))); \
        zA = zB; zB = zc;                                                     \
        mixn = (float)zA;                                                     \
      } else {                                                                \
        float p = 0.f;                                                        \
        _Pragma("unroll")                                                     \
        for (int r = 0; r < 4; ++r) {                                         \
          double xr = (double)((mk >> (4 * q + r)) & 1u);                     \
          double y2 = fma(twoa4[r], yd1a[r], fma(na24[r], yd0a[r], c2a4[r] * xr)); \
          yd0a[r] = yd1a[r]; yd1a[r] = y2;                                    \
          p = fmaf(cden4[r], (float)y2, p);                                   \
        }                                                                     \
        p += __shfl_xor(p, 16); p += __shfl_xor(p, 32);                       \
        mixn = mix1; mix1 = p;                                                \
      }                                                                       \
      _Pragma("unroll")                                                       \
      for (int i = 10; i >= 1; --i) sig[i] = sig[i - 1];                      \
      sig[0] = sg;                                                            \
      mixu = mixn;                                                            \
    }

    for (int I = 0; I < NGRP; ++I) {
      // prefetch next group's o (slot (I+1)%3, written at iter I-1) and synT
      const int sl = (I + 1) % 3;
      float4 p0 = *(const float4*)&oPart[sl][0][s][0];
      float4 p1 = *(const float4*)&oPart[sl][1][s][0];
      float4 p2 = *(const float4*)&oPart[sl][2][s][0];
      float4 svn;
      if (I + 1 < NGRP) svn = *(const float4*)(synT + (long)s * T_DATA + 4 * (I + 1));
      else { svn.x = 0.f; svn.y = 0.f; svn.z = 0.f; svn.w = 0.f; }

      unsigned m0, m1, m2, m3;
      STEP(0, oc.x, sv.x, m0)
      STEP(1, oc.y, sv.y, m1)
      STEP(2, oc.z, sv.z, m2)
      STEP(3, oc.w, sv.w, m3)

      // ring write: spikes t=4I..4I+3 -> positions u..u+3 (+mirror)
      if (l < 16) {
        int u = (4 * I) & 255;
        float4 w; w.x = sig[3]; w.y = sig[2]; w.z = sig[1]; w.w = sig[0];
        *(float4*)&ring[s][u] = w;
        if (u < 192) *(float4*)&ring[s][u + 256] = w;
      }
      // coalesced spike store: lane l -> (step q, subunit s)
      unsigned mm = (q & 1) ? ((q & 2) ? m3 : m1) : ((q & 2) ? m2 : m0);
      spk_out[(I << 6) + l] = (float)((mm >> s) & 1u);

      float4 onx; onx.x = p0.x + p1.x + p2.x; onx.y = p0.y + p1.y + p2.y;
      onx.z = p0.z + p1.z + p2.z; onx.w = p0.w + p1.w + p2.w;
      oc = onx; sv = svn;
      __syncthreads();
    }
#undef STEP
  } else {
    // ================= gather waves (w = 0..2) =================
    const int w = widx - 1;
    const float* hrow = filt + (48 + s) * TNO;
    const int off = 199 - 64 * w - 16 * q;      // coeff idx = off + K - i, i=0..15
    float ca[19];
#pragma unroll
    for (int n = 0; n < 19; ++n) {
      int idx = off - 15 + n;
      ca[n] = (idx <= 199) ? hrow[idx] : 0.f;   // idx >= 8 always
    }
    v2f pr[18];                                  // pr[m-1] = {ca[m], ca[m-1]}
#pragma unroll
    for (int m = 1; m <= 18; ++m) { pr[m - 1].x = ca[m]; pr[m - 1].y = ca[m - 1]; }
#define PR(m) pr[(m) - 1]

    for (int I = 0; I < NGRP; ++I) {
      const int T = I + 2;
      int Pe = (4 * T - 9) & 255;
      if (Pe < 191) Pe += 256;
      const int Bq = Pe - 191 + 64 * w + 16 * q;  // 16B-aligned (Pe%4==3)
      const float4* rp = (const float4*)&ring[s][Bq];
      float4 V0 = rp[0], V1 = rp[1], V2 = rp[2], V3 = rp[3];

      v2f a0 = {0.f, 0.f}, a1 = {0.f, 0.f}, a2 = {0.f, 0.f}, a3 = {0.f, 0.f};
#define MAC4(V, J)                                                     \
      {                                                                \
        v2f A; A.x = (V).x; A.y = (V).y;                               \
        v2f B; B.x = (V).z; B.y = (V).w;                               \
        a0 += PR(15 - 4 * (J)) * A; a0 += PR(13 - 4 * (J)) * B;        \
        a1 += PR(16 - 4 * (J)) * A; a1 += PR(14 - 4 * (J)) * B;        \
        a2 += PR(17 - 4 * (J)) * A; a2 += PR(15 - 4 * (J)) * B;        \
        a3 += PR(18 - 4 * (J)) * A; a3 += PR(16 - 4 * (J)) * B;        \
      }
      MAC4(V0, 0) MAC4(V1, 1) MAC4(V2, 2) MAC4(V3, 3)
#undef MAC4
      float o0 = a0.x + a0.y, o1 = a1.x + a1.y, o2 = a2.x + a2.y, o3 = a3.x + a3.y;
      o0 += __shfl_xor(o0, 16); o0 += __shfl_xor(o0, 32);
      o1 += __shfl_xor(o1, 16); o1 += __shfl_xor(o1, 32);
      o2 += __shfl_xor(o2, 16); o2 += __shfl_xor(o2, 32);
      o3 += __shfl_xor(o3, 16); o3 += __shfl_xor(o3, 32);
      if (l < 16) {
        float4 ov; ov.x = o0; ov.y = o1; ov.z = o2; ov.w = o3;
        *(float4*)&oPart[T % 3][w][s][0] = ov;
      }
      __syncthreads();
    }
#undef PR
  }
}

extern "C" void kernel_launch(void* const* d_in, const int* in_sizes, int n_in,
                              void* d_out, int out_size, void* d_ws, size_t ws_size,
                              hipStream_t stream) {
  const float* S_e     = (const float*)d_in[0];
  const float* S_i     = (const float*)d_in[1];
  const float* C_den   = (const float*)d_in[2];
  const float* C_syn_e = (const float*)d_in[3];
  const float* C_syn_i = (const float*)d_in[4];
  const float* Tau_e   = (const float*)d_in[5];
  const float* Tau_i   = (const float*)d_in[6];
  const float* W_e     = (const float*)d_in[7];
  const float* W_i     = (const float*)d_in[8];
  const float* D_e     = (const float*)d_in[9];
  const float* D_i     = (const float*)d_in[10];
  const float* Tau_spk = (const float*)d_in[11];
  const float* W_spk   = (const float*)d_in[12];
  const float* W_hist  = (const float*)d_in[13];
  const float* Theta   = (const float*)d_in[14];

  float* out     = (float*)d_out;
  float* spk_out = out;            // 20000*16
  float* filt    = out + 320000;   // 64*200

  float* ws    = (float*)d_ws;
  float* syn_e = ws;               // 320000
  float* syn_i = ws + 320000;      // 320000
  float* synT  = ws + 640000;      // 320000 (transposed [s][t])

  filters_k<<<50, 256, 0, stream>>>(Tau_e, Tau_i, W_e, W_i, D_e, D_i,
                                    Tau_spk, W_spk, W_hist, filt);
  synmm_k<<<1250, 256, 0, stream>>>(S_e, C_syn_e, syn_e, E_NO_C);
  synmm_k<<<1250, 256, 0, stream>>>(S_i, C_syn_i, syn_i, I_NO_C);
  conv_k<<<1250, 256, 0, stream>>>(syn_e, syn_i, filt, Theta, synT);
  scan4_k<<<1, 256, 0, stream>>>(synT, filt, C_den, Tau_spk, W_spk, spk_out);
}